// Round 1
// baseline (1146.057 us; speedup 1.0000x reference)
//
#include <hip/hip_runtime.h>

constexpr int BN = 4;       // batches
constexpr int NV = 25600;   // vertices (160*160)
constexpr int DD = 64;      // D

// ---------------- ws layout ----------------
// [0, (NV+1)*4)        : row_ptr (int)
// [128 KiB, +64 KiB)   : M, BN x 64 x 64 fp32

__global__ void rowptr_kernel(const int* __restrict__ e0, int E, int* __restrict__ row_ptr) {
    int i = blockIdx.x * blockDim.x + threadIdx.x;
    if (i > NV) return;
    int lo = 0, hi = E;
    while (lo < hi) {
        int mid = (lo + hi) >> 1;
        if (e0[mid] < i) lo = mid + 1; else hi = mid;
    }
    row_ptr[i] = lo;
}

// One wave per node (lane = d column). 4 nodes per block per chunk iteration.
// Per chunk: stage J3/BTJ rows (A) and LJ/-CBTJ rows (B) in LDS, then a
// rank-24 update into per-thread 4x4 fp32 accumulators of the 64x64 M.
__global__ __launch_bounds__(256) void node_kernel(
    const float* __restrict__ x, const float* __restrict__ J,
    const int* __restrict__ e1, const int* __restrict__ row_ptr,
    float* __restrict__ M)
{
    const int b    = blockIdx.y;
    const int w    = threadIdx.x >> 6;   // wave id 0..3
    const int lane = threadIdx.x & 63;   // d index

    __shared__ float SA[24][64];
    __shared__ float SB[24][64];

    const int d0  = (threadIdx.x & 15) * 4;   // output row tile
    const int eo0 = (threadIdx.x >> 4) * 4;   // output col tile
    float macc[4][4];
#pragma unroll
    for (int i = 0; i < 4; i++)
#pragma unroll
        for (int j = 0; j < 4; j++) macc[i][j] = 0.f;

    const float* xb = x + (size_t)b * NV * 3;
    const float* Jb = J + (size_t)b * 3 * NV * DD;

    for (int chunk = blockIdx.x; chunk < NV / 4; chunk += gridDim.x) {
        // ---- phase 1: wave w computes node n's 3xD vectors ----
        const int n = chunk * 4 + w;
        const float xn0 = xb[n * 3 + 0], xn1 = xb[n * 3 + 1], xn2 = xb[n * 3 + 2];
        const float* Jn = Jb + n * 3 * DD + lane;
        const float jn0 = Jn[0], jn1 = Jn[DD], jn2 = Jn[2 * DD];
        float lj0 = 0, lj1 = 0, lj2 = 0, bt0 = 0, bt1 = 0, bt2 = 0;
        float cxx = 0, cxy = 0, cxz = 0, cyy = 0, cyz = 0, czz = 0;
        const int beg = row_ptr[n], end = row_ptr[n + 1];
        for (int e = beg; e < end; e++) {
            const int m = e1[e];
            const float v0 = xn0 - xb[m * 3 + 0];
            const float v1 = xn1 - xb[m * 3 + 1];
            const float v2 = xn2 - xb[m * 3 + 2];
            const float* Jm = Jb + m * 3 * DD + lane;
            const float t0 = Jm[0] - jn0, t1 = Jm[DD] - jn1, t2 = Jm[2 * DD] - jn2;
            lj0 -= t0; lj1 -= t1; lj2 -= t2;      // LJ/2 = sum (jn - jm)
            // BTJ += v x t  (v = xn - xm, t = jm - jn)
            bt0 += v1 * t2 - v2 * t1;
            bt1 += v2 * t0 - v0 * t2;
            bt2 += v0 * t1 - v1 * t0;
            const float s2 = v0 * v0 + v1 * v1 + v2 * v2;
            cxx += s2 - v0 * v0; cyy += s2 - v1 * v1; czz += s2 - v2 * v2;
            cxy -= v0 * v1; cxz -= v0 * v2; cyz -= v1 * v2;
        }
        lj0 *= 2.f; lj1 *= 2.f; lj2 *= 2.f;
        // symmetric 3x3 inverse of C via adjugate
        const float co00 = cyy * czz - cyz * cyz;
        const float co01 = cxz * cyz - cxy * czz;
        const float co02 = cxy * cyz - cxz * cyy;
        const float det  = cxx * co00 + cxy * co01 + cxz * co02;
        const float id   = 1.0f / det;
        const float i00 = co00 * id, i01 = co01 * id, i02 = co02 * id;
        const float i11 = (cxx * czz - cxz * cxz) * id;
        const float i12 = (cxz * cxy - cxx * cyz) * id;
        const float i22 = (cxx * cyy - cxy * cxy) * id;
        const float cb0 = i00 * bt0 + i01 * bt1 + i02 * bt2;
        const float cb1 = i01 * bt0 + i11 * bt1 + i12 * bt2;
        const float cb2 = i02 * bt0 + i12 * bt1 + i22 * bt2;

        SA[w * 6 + 0][lane] = jn0; SA[w * 6 + 1][lane] = jn1; SA[w * 6 + 2][lane] = jn2;
        SA[w * 6 + 3][lane] = bt0; SA[w * 6 + 4][lane] = bt1; SA[w * 6 + 5][lane] = bt2;
        SB[w * 6 + 0][lane] = lj0; SB[w * 6 + 1][lane] = lj1; SB[w * 6 + 2][lane] = lj2;
        SB[w * 6 + 3][lane] = -cb0; SB[w * 6 + 4][lane] = -cb1; SB[w * 6 + 5][lane] = -cb2;
        __syncthreads();

        // ---- phase 2: rank-24 update ----
#pragma unroll
        for (int k = 0; k < 24; k++) {
            const float4 a4 = *reinterpret_cast<const float4*>(&SA[k][d0]);
            const float4 b4 = *reinterpret_cast<const float4*>(&SB[k][eo0]);
            macc[0][0] += a4.x * b4.x; macc[0][1] += a4.x * b4.y; macc[0][2] += a4.x * b4.z; macc[0][3] += a4.x * b4.w;
            macc[1][0] += a4.y * b4.x; macc[1][1] += a4.y * b4.y; macc[1][2] += a4.y * b4.z; macc[1][3] += a4.y * b4.w;
            macc[2][0] += a4.z * b4.x; macc[2][1] += a4.z * b4.y; macc[2][2] += a4.z * b4.z; macc[2][3] += a4.z * b4.w;
            macc[3][0] += a4.w * b4.x; macc[3][1] += a4.w * b4.y; macc[3][2] += a4.w * b4.z; macc[3][3] += a4.w * b4.w;
        }
        __syncthreads();
    }

    float* Mb = M + b * 4096;
#pragma unroll
    for (int i = 0; i < 4; i++)
#pragma unroll
        for (int j = 0; j < 4; j++)
            atomicAdd(&Mb[(d0 + i) * 64 + (eo0 + j)], macc[i][j]);
}

// Parallel cyclic Jacobi eigensolver, one block per batch matrix.
__global__ __launch_bounds__(256) void jacobi_kernel(const float* __restrict__ M,
                                                     float* __restrict__ out)
{
    const int b = blockIdx.x;
    const int tid = threadIdx.x;
    __shared__ float A[64][65];
    __shared__ float cS[32], sS[32];
    __shared__ int pS[32], qS[32];
    __shared__ float red[64];

    const float* Mb = M + b * 4096;
    for (int i = tid; i < 4096; i += 256) A[i >> 6][i & 63] = Mb[i];
    __syncthreads();

    const int SWEEPS = 7;
    for (int sw = 0; sw < SWEEPS; sw++) {
        for (int r = 0; r < 63; r++) {
            if (tid < 32) {
                const int i = tid;
                const int p = (i == 0) ? 0 : (1 + (i - 1 + r) % 63);
                const int q = 1 + (62 - i + r) % 63;
                const float app = A[p][p], aqq = A[q][q], apq = A[p][q];
                float c = 1.f, s = 0.f;
                if (fabsf(apq) > 1e-20f) {
                    const float tau = (aqq - app) / (2.f * apq);
                    float t = 1.f / (fabsf(tau) + sqrtf(1.f + tau * tau));
                    if (tau < 0.f) t = -t;
                    c = 1.f / sqrtf(1.f + t * t);
                    s = t * c;
                }
                pS[tid] = p; qS[tid] = q; cS[tid] = c; sS[tid] = s;
            }
            __syncthreads();
            // column update: A <- A * J
            for (int idx = tid; idx < 2048; idx += 256) {
                const int pr = idx >> 6, i = idx & 63;
                const int p = pS[pr], q = qS[pr];
                const float c = cS[pr], s = sS[pr];
                const float aip = A[i][p], aiq = A[i][q];
                A[i][p] = c * aip - s * aiq;
                A[i][q] = s * aip + c * aiq;
            }
            __syncthreads();
            // row update: A <- J^T * A
            for (int idx = tid; idx < 2048; idx += 256) {
                const int pr = idx >> 6, j = idx & 63;
                const int p = pS[pr], q = qS[pr];
                const float c = cS[pr], s = sS[pr];
                const float apj = A[p][j], aqj = A[q][j];
                A[p][j] = c * apj - s * aqj;
                A[q][j] = s * apj + c * aqj;
            }
            __syncthreads();
        }
    }

    if (tid < 64) {
        const float v = A[tid][tid];
        red[tid] = (v > 0.f) ? sqrtf(v) : 0.f;
    }
    __syncthreads();
    if (tid == 0) {
        float sacc = 0.f;
        for (int i = 0; i < 64; i++) sacc += red[i];
        atomicAdd(out, sacc * (1.0f / BN));
    }
}

extern "C" void kernel_launch(void* const* d_in, const int* in_sizes, int n_in,
                              void* d_out, int out_size, void* d_ws, size_t ws_size,
                              hipStream_t stream) {
    const float* x  = (const float*)d_in[0];
    const float* J  = (const float*)d_in[1];
    const int*   e0 = (const int*)d_in[2];
    const int*   e1 = (const int*)d_in[3];
    const int E = in_sizes[2];

    int*   row_ptr = (int*)d_ws;
    float* M       = (float*)((char*)d_ws + 128 * 1024);

    hipMemsetAsync(M, 0, BN * 64 * 64 * sizeof(float), stream);
    hipMemsetAsync(d_out, 0, sizeof(float), stream);

    rowptr_kernel<<<(NV + 1 + 255) / 256, 256, 0, stream>>>(e0, E, row_ptr);
    node_kernel<<<dim3(160, BN), 256, 0, stream>>>(x, J, e1, row_ptr, M);
    jacobi_kernel<<<BN, 256, 0, stream>>>(M, (float*)d_out);
}

// Round 3
// 399.327 us; speedup vs baseline: 2.8700x; 2.8700x over previous
//
#include <hip/hip_runtime.h>

constexpr int BN = 4;       // batches
constexpr int NV = 25600;   // vertices (160*160)
constexpr int DD = 64;      // D
constexpr int PP = 72;      // bf16 LDS row pitch (keeps 16B alignment for short8)
constexpr int NS_ITERS = 22;

typedef __attribute__((ext_vector_type(8))) short short8;
typedef __attribute__((ext_vector_type(4))) float floatx4;

__device__ __forceinline__ unsigned short f2bf(float x) {
    unsigned u = __float_as_uint(x);
    u += 0x7fffu + ((u >> 16) & 1u);        // round-to-nearest-even
    return (unsigned short)(u >> 16);
}
__device__ __forceinline__ float bf2f(unsigned short h) {
    return __uint_as_float(((unsigned)h) << 16);
}

__global__ void rowptr_kernel(const int* __restrict__ e0, int E, int* __restrict__ row_ptr) {
    int i = blockIdx.x * blockDim.x + threadIdx.x;
    if (i > NV) return;
    int lo = 0, hi = E;
    while (lo < hi) {
        int mid = (lo + hi) >> 1;
        if (e0[mid] < i) lo = mid + 1; else hi = mid;
    }
    row_ptr[i] = lo;
}

// One wave per node (lane = d column). 4 nodes per block per chunk iteration.
__global__ __launch_bounds__(256) void node_kernel(
    const float* __restrict__ x, const float* __restrict__ J,
    const int* __restrict__ e1, const int* __restrict__ row_ptr,
    float* __restrict__ M)
{
    const int b    = blockIdx.y;
    const int w    = threadIdx.x >> 6;   // wave id 0..3
    const int lane = threadIdx.x & 63;   // d index

    __shared__ float SA[24][64];
    __shared__ float SB[24][64];

    const int d0  = (threadIdx.x & 15) * 4;   // output row tile
    const int eo0 = (threadIdx.x >> 4) * 4;   // output col tile
    float macc[4][4];
#pragma unroll
    for (int i = 0; i < 4; i++)
#pragma unroll
        for (int j = 0; j < 4; j++) macc[i][j] = 0.f;

    const float* xb = x + (size_t)b * NV * 3;
    const float* Jb = J + (size_t)b * 3 * NV * DD;

    for (int chunk = blockIdx.x; chunk < NV / 4; chunk += gridDim.x) {
        const int n = chunk * 4 + w;
        const float xn0 = xb[n * 3 + 0], xn1 = xb[n * 3 + 1], xn2 = xb[n * 3 + 2];
        const float* Jn = Jb + n * 3 * DD + lane;
        const float jn0 = Jn[0], jn1 = Jn[DD], jn2 = Jn[2 * DD];
        float lj0 = 0, lj1 = 0, lj2 = 0, bt0 = 0, bt1 = 0, bt2 = 0;
        float cxx = 0, cxy = 0, cxz = 0, cyy = 0, cyz = 0, czz = 0;
        const int beg = row_ptr[n], end = row_ptr[n + 1];
        for (int e = beg; e < end; e++) {
            const int m = e1[e];
            const float v0 = xn0 - xb[m * 3 + 0];
            const float v1 = xn1 - xb[m * 3 + 1];
            const float v2 = xn2 - xb[m * 3 + 2];
            const float* Jm = Jb + m * 3 * DD + lane;
            const float t0 = Jm[0] - jn0, t1 = Jm[DD] - jn1, t2 = Jm[2 * DD] - jn2;
            lj0 -= t0; lj1 -= t1; lj2 -= t2;
            bt0 += v1 * t2 - v2 * t1;
            bt1 += v2 * t0 - v0 * t2;
            bt2 += v0 * t1 - v1 * t0;
            const float s2 = v0 * v0 + v1 * v1 + v2 * v2;
            cxx += s2 - v0 * v0; cyy += s2 - v1 * v1; czz += s2 - v2 * v2;
            cxy -= v0 * v1; cxz -= v0 * v2; cyz -= v1 * v2;
        }
        lj0 *= 2.f; lj1 *= 2.f; lj2 *= 2.f;
        const float co00 = cyy * czz - cyz * cyz;
        const float co01 = cxz * cyz - cxy * czz;
        const float co02 = cxy * cyz - cxz * cyy;
        const float det  = cxx * co00 + cxy * co01 + cxz * co02;
        const float id   = 1.0f / det;
        const float i00 = co00 * id, i01 = co01 * id, i02 = co02 * id;
        const float i11 = (cxx * czz - cxz * cxz) * id;
        const float i12 = (cxz * cxy - cxx * cyz) * id;
        const float i22 = (cxx * cyy - cxy * cxy) * id;
        const float cb0 = i00 * bt0 + i01 * bt1 + i02 * bt2;
        const float cb1 = i01 * bt0 + i11 * bt1 + i12 * bt2;
        const float cb2 = i02 * bt0 + i12 * bt1 + i22 * bt2;

        SA[w * 6 + 0][lane] = jn0; SA[w * 6 + 1][lane] = jn1; SA[w * 6 + 2][lane] = jn2;
        SA[w * 6 + 3][lane] = bt0; SA[w * 6 + 4][lane] = bt1; SA[w * 6 + 5][lane] = bt2;
        SB[w * 6 + 0][lane] = lj0; SB[w * 6 + 1][lane] = lj1; SB[w * 6 + 2][lane] = lj2;
        SB[w * 6 + 3][lane] = -cb0; SB[w * 6 + 4][lane] = -cb1; SB[w * 6 + 5][lane] = -cb2;
        __syncthreads();

#pragma unroll
        for (int k = 0; k < 24; k++) {
            const float4 a4 = *reinterpret_cast<const float4*>(&SA[k][d0]);
            const float4 b4 = *reinterpret_cast<const float4*>(&SB[k][eo0]);
            macc[0][0] += a4.x * b4.x; macc[0][1] += a4.x * b4.y; macc[0][2] += a4.x * b4.z; macc[0][3] += a4.x * b4.w;
            macc[1][0] += a4.y * b4.x; macc[1][1] += a4.y * b4.y; macc[1][2] += a4.y * b4.z; macc[1][3] += a4.y * b4.w;
            macc[2][0] += a4.z * b4.x; macc[2][1] += a4.z * b4.y; macc[2][2] += a4.z * b4.z; macc[2][3] += a4.z * b4.w;
            macc[3][0] += a4.w * b4.x; macc[3][1] += a4.w * b4.y; macc[3][2] += a4.w * b4.z; macc[3][3] += a4.w * b4.w;
        }
        __syncthreads();
    }

    float* Mb = M + b * 4096;
#pragma unroll
    for (int i = 0; i < 4; i++)
#pragma unroll
        for (int j = 0; j < 4; j++)
            atomicAdd(&Mb[(d0 + i) * 64 + (eo0 + j)], macc[i][j]);
}

// ---------------------------------------------------------------------------
// trace(sqrtm(M + delta*I)) via coupled Newton-Schulz, bf16-split MFMA matmuls.
// One block (4 waves) per batch matrix. All iterates are symmetric (polynomials
// in M), so MFMA B-operand fragments read row-major — no transposes.
// Update: Y' = Y*W, Z' = W*Z with W = 1.5I - 0.5*Z*Y  (W carries the 1/2).
// ---------------------------------------------------------------------------
__global__ __launch_bounds__(256) void ns_sqrt_kernel(const float* __restrict__ M,
                                                      float* __restrict__ out)
{
    const int b    = blockIdx.x;
    const int tid  = threadIdx.x;
    const int w    = tid >> 6;
    const int lane = tid & 63;
    const int quad = lane >> 4;
    const int mrow = lane & 15;
    const int r0   = w * 16;             // this wave's output row strip

    __shared__ __align__(16) unsigned short Yh[64 * PP], Yl[64 * PP];
    __shared__ __align__(16) unsigned short Zh[64 * PP], Zl[64 * PP];
    __shared__ __align__(16) unsigned short Wh[64 * PP], Wl[64 * PP];
    __shared__ float tr_s;

    const float* Mb = M + b * 4096;

    // trace of M (one wave)
    if (tid < 64) {
        float d = Mb[tid * 64 + tid];
#pragma unroll
        for (int off = 32; off; off >>= 1) d += __shfl_down(d, off, 64);
        if (tid == 0) tr_s = d;
    }
    __syncthreads();
    const float tr    = tr_s;
    const float delta = 3e-5f * tr;
    const float cnorm = tr + 64.f * delta;   // >= lambda_max of shifted matrix
    const float inv_c = 1.f / cnorm;

    // Y0 = (M + delta I)/c  (bf16 hi/lo split), Z0 = I
    for (int i = tid; i < 4096; i += 256) {
        const int r = i >> 6, col = i & 63;
        float v = Mb[i] * inv_c;
        if (r == col) v += delta * inv_c;
        const unsigned short h = f2bf(v);
        Yh[r * PP + col] = h;
        Yl[r * PP + col] = f2bf(v - bf2f(h));
        Zh[r * PP + col] = (r == col) ? (unsigned short)0x3f80 : (unsigned short)0;
        Zl[r * PP + col] = 0;
    }
    __syncthreads();

    const floatx4 zero4 = {0.f, 0.f, 0.f, 0.f};

    for (int it = 0; it < NS_ITERS; ++it) {
        // ---- phase 1: W = 1.5 I - 0.5 * (Z*Y) ----
        floatx4 accT[4];
#pragma unroll
        for (int c = 0; c < 4; c++) accT[c] = zero4;
#pragma unroll
        for (int ks = 0; ks < 2; ks++) {
            const int ko = ks * 32 + quad * 8;
            const short8 zah = *(const short8*)&Zh[(r0 + mrow) * PP + ko];
            const short8 zal = *(const short8*)&Zl[(r0 + mrow) * PP + ko];
#pragma unroll
            for (int c = 0; c < 4; c++) {
                const short8 ybh = *(const short8*)&Yh[(c * 16 + mrow) * PP + ko];
                const short8 ybl = *(const short8*)&Yl[(c * 16 + mrow) * PP + ko];
                accT[c] = __builtin_amdgcn_mfma_f32_16x16x32_bf16(zah, ybh, accT[c], 0, 0, 0);
                accT[c] = __builtin_amdgcn_mfma_f32_16x16x32_bf16(zah, ybl, accT[c], 0, 0, 0);
                accT[c] = __builtin_amdgcn_mfma_f32_16x16x32_bf16(zal, ybh, accT[c], 0, 0, 0);
            }
        }
        __syncthreads();   // T complete in regs; Wh/Wl free to overwrite
#pragma unroll
        for (int c = 0; c < 4; c++) {
#pragma unroll
            for (int r = 0; r < 4; r++) {
                const int row = r0 + quad * 4 + r;       // C/D layout: row=quad*4+reg
                const int col = c * 16 + mrow;           //             col=lane&15
                float v = -0.5f * accT[c][r];
                if (row == col) v += 1.5f;
                const unsigned short h = f2bf(v);
                Wh[row * PP + col] = h;
                Wl[row * PP + col] = f2bf(v - bf2f(h));
            }
        }
        __syncthreads();

        // ---- phase 2: Ynew = Y*W, Znew = W*Z (W carries the 1/2 factor) ----
        floatx4 accY[4], accZ[4];
#pragma unroll
        for (int c = 0; c < 4; c++) { accY[c] = zero4; accZ[c] = zero4; }
#pragma unroll
        for (int ks = 0; ks < 2; ks++) {
            const int ko = ks * 32 + quad * 8;
            const short8 yah = *(const short8*)&Yh[(r0 + mrow) * PP + ko];
            const short8 yal = *(const short8*)&Yl[(r0 + mrow) * PP + ko];
            const short8 wah = *(const short8*)&Wh[(r0 + mrow) * PP + ko];
            const short8 wal = *(const short8*)&Wl[(r0 + mrow) * PP + ko];
#pragma unroll
            for (int c = 0; c < 4; c++) {
                const short8 wbh = *(const short8*)&Wh[(c * 16 + mrow) * PP + ko];
                const short8 wbl = *(const short8*)&Wl[(c * 16 + mrow) * PP + ko];
                accY[c] = __builtin_amdgcn_mfma_f32_16x16x32_bf16(yah, wbh, accY[c], 0, 0, 0);
                accY[c] = __builtin_amdgcn_mfma_f32_16x16x32_bf16(yah, wbl, accY[c], 0, 0, 0);
                accY[c] = __builtin_amdgcn_mfma_f32_16x16x32_bf16(yal, wbh, accY[c], 0, 0, 0);
                const short8 zbh = *(const short8*)&Zh[(c * 16 + mrow) * PP + ko];
                const short8 zbl = *(const short8*)&Zl[(c * 16 + mrow) * PP + ko];
                accZ[c] = __builtin_amdgcn_mfma_f32_16x16x32_bf16(wah, zbh, accZ[c], 0, 0, 0);
                accZ[c] = __builtin_amdgcn_mfma_f32_16x16x32_bf16(wah, zbl, accZ[c], 0, 0, 0);
                accZ[c] = __builtin_amdgcn_mfma_f32_16x16x32_bf16(wal, zbh, accZ[c], 0, 0, 0);
            }
        }
        __syncthreads();   // all reads of Y,Z done; safe to overwrite in place
#pragma unroll
        for (int c = 0; c < 4; c++) {
#pragma unroll
            for (int r = 0; r < 4; r++) {
                const int row = r0 + quad * 4 + r;
                const int col = c * 16 + mrow;
                const float vy = accY[c][r];   // no extra 0.5 — W carries it
                const float vz = accZ[c][r];
                unsigned short h = f2bf(vy);
                Yh[row * PP + col] = h;
                Yl[row * PP + col] = f2bf(vy - bf2f(h));
                h = f2bf(vz);
                Zh[row * PP + col] = h;
                Zl[row * PP + col] = f2bf(vz - bf2f(h));
            }
        }
        __syncthreads();
    }

    // trace(Y) * sqrt(c): hi+lo recovers ~16-bit mantissa per diag element
    if (tid < 64) {
        float d = bf2f(Yh[tid * PP + tid]) + bf2f(Yl[tid * PP + tid]);
#pragma unroll
        for (int off = 32; off; off >>= 1) d += __shfl_down(d, off, 64);
        if (tid == 0) atomicAdd(out, d * sqrtf(cnorm) * (1.0f / BN));
    }
}

extern "C" void kernel_launch(void* const* d_in, const int* in_sizes, int n_in,
                              void* d_out, int out_size, void* d_ws, size_t ws_size,
                              hipStream_t stream) {
    const float* x  = (const float*)d_in[0];
    const float* J  = (const float*)d_in[1];
    const int*   e0 = (const int*)d_in[2];
    const int*   e1 = (const int*)d_in[3];
    const int E = in_sizes[2];

    int*   row_ptr = (int*)d_ws;
    float* M       = (float*)((char*)d_ws + 128 * 1024);

    hipMemsetAsync(M, 0, BN * 64 * 64 * sizeof(float), stream);
    hipMemsetAsync(d_out, 0, sizeof(float), stream);

    rowptr_kernel<<<(NV + 1 + 255) / 256, 256, 0, stream>>>(e0, E, row_ptr);
    node_kernel<<<dim3(160, BN), 256, 0, stream>>>(x, J, e1, row_ptr, M);
    ns_sqrt_kernel<<<BN, 256, 0, stream>>>(M, (float*)d_out);
}

// Round 4
// 341.703 us; speedup vs baseline: 3.3540x; 1.1686x over previous
//
#include <hip/hip_runtime.h>

constexpr int BN = 4;       // batches
constexpr int NV = 25600;   // vertices (160*160)
constexpr int DD = 64;      // D
constexpr int PP = 72;      // bf16 LDS row pitch (keeps 16B alignment for short8)
constexpr int NS_ITERS = 18;

typedef __attribute__((ext_vector_type(8))) short short8;
typedef __attribute__((ext_vector_type(4))) float floatx4;

__device__ __forceinline__ unsigned short f2bf(float x) {
    unsigned u = __float_as_uint(x);
    u += 0x7fffu + ((u >> 16) & 1u);        // round-to-nearest-even
    return (unsigned short)(u >> 16);
}
__device__ __forceinline__ float bf2f(unsigned short h) {
    return __uint_as_float(((unsigned)h) << 16);
}

__global__ void rowptr_kernel(const int* __restrict__ e0, int E, int* __restrict__ row_ptr) {
    int i = blockIdx.x * blockDim.x + threadIdx.x;
    if (i > NV) return;
    int lo = 0, hi = E;
    while (lo < hi) {
        int mid = (lo + hi) >> 1;
        if (e0[mid] < i) lo = mid + 1; else hi = mid;
    }
    row_ptr[i] = lo;
}

// One wave per node (lane = d column). 4 nodes per block per chunk iteration.
// Uniform work (indices, x) on the scalar pipe via readfirstlane; neighbor
// loads unrolled to max-degree 6 (grid mesh) so all VMEM issues up front.
__global__ __launch_bounds__(256, 4) void node_kernel(
    const float* __restrict__ x, const float* __restrict__ J,
    const int* __restrict__ e1, const int* __restrict__ row_ptr,
    float* __restrict__ M)
{
    const int b    = blockIdx.y;
    const int w    = __builtin_amdgcn_readfirstlane(threadIdx.x >> 6);  // uniform wave id
    const int lane = threadIdx.x & 63;   // d index

    __shared__ float SA[24][64];
    __shared__ float SB[24][64];

    const int d0  = (threadIdx.x & 15) * 4;   // output row tile
    const int eo0 = (threadIdx.x >> 4) * 4;   // output col tile
    float macc[4][4];
#pragma unroll
    for (int i = 0; i < 4; i++)
#pragma unroll
        for (int j = 0; j < 4; j++) macc[i][j] = 0.f;

    const float* xb = x + (size_t)b * NV * 3;
    const float* Jb = J + (size_t)b * 3 * NV * DD;

    for (int chunk = blockIdx.x; chunk < NV / 4; chunk += gridDim.x) {
        const int n   = chunk * 4 + w;
        const int beg = row_ptr[n];
        const int deg = row_ptr[n + 1] - beg;

        // neighbor indices (scalar loads; OOB-clamped, padded with self -> zero contrib)
        int mm[6];
#pragma unroll
        for (int k = 0; k < 6; k++) {
            const int idx = beg + ((k < deg) ? k : 0);
            const int mv  = e1[idx];
            mm[k] = (k < deg) ? mv : n;
        }

        // issue ALL global loads up front (one latency window)
        const float* Jn = Jb + n * 3 * DD + lane;
        const float jn0 = Jn[0], jn1 = Jn[DD], jn2 = Jn[2 * DD];
        float jm0[6], jm1[6], jm2[6];
#pragma unroll
        for (int k = 0; k < 6; k++) {
            const float* Jm = Jb + mm[k] * 3 * DD + lane;
            jm0[k] = Jm[0]; jm1[k] = Jm[DD]; jm2[k] = Jm[2 * DD];
        }
        const float xn0 = xb[n * 3 + 0], xn1 = xb[n * 3 + 1], xn2 = xb[n * 3 + 2];
        float va0[6], va1[6], va2[6];
#pragma unroll
        for (int k = 0; k < 6; k++) {
            va0[k] = xn0 - xb[mm[k] * 3 + 0];
            va1[k] = xn1 - xb[mm[k] * 3 + 1];
            va2[k] = xn2 - xb[mm[k] * 3 + 2];
        }

        float lj0 = 0, lj1 = 0, lj2 = 0, bt0 = 0, bt1 = 0, bt2 = 0;
        float cxx = 0, cxy = 0, cxz = 0, cyy = 0, cyz = 0, czz = 0;
#pragma unroll
        for (int k = 0; k < 6; k++) {
            const float v0 = va0[k], v1 = va1[k], v2 = va2[k];
            const float t0 = jm0[k] - jn0, t1 = jm1[k] - jn1, t2 = jm2[k] - jn2;
            lj0 -= t0; lj1 -= t1; lj2 -= t2;
            bt0 += v1 * t2 - v2 * t1;
            bt1 += v2 * t0 - v0 * t2;
            bt2 += v0 * t1 - v1 * t0;
            const float s2 = v0 * v0 + v1 * v1 + v2 * v2;
            cxx += s2 - v0 * v0; cyy += s2 - v1 * v1; czz += s2 - v2 * v2;
            cxy -= v0 * v1; cxz -= v0 * v2; cyz -= v1 * v2;
        }
        // safety tail (never taken on this mesh: max degree 6)
        for (int e = beg + 6; e < beg + deg; e++) {
            const int m = e1[e];
            const float v0 = xn0 - xb[m * 3 + 0];
            const float v1 = xn1 - xb[m * 3 + 1];
            const float v2 = xn2 - xb[m * 3 + 2];
            const float* Jm = Jb + m * 3 * DD + lane;
            const float t0 = Jm[0] - jn0, t1 = Jm[DD] - jn1, t2 = Jm[2 * DD] - jn2;
            lj0 -= t0; lj1 -= t1; lj2 -= t2;
            bt0 += v1 * t2 - v2 * t1;
            bt1 += v2 * t0 - v0 * t2;
            bt2 += v0 * t1 - v1 * t0;
            const float s2 = v0 * v0 + v1 * v1 + v2 * v2;
            cxx += s2 - v0 * v0; cyy += s2 - v1 * v1; czz += s2 - v2 * v2;
            cxy -= v0 * v1; cxz -= v0 * v2; cyz -= v1 * v2;
        }

        lj0 *= 2.f; lj1 *= 2.f; lj2 *= 2.f;
        const float co00 = cyy * czz - cyz * cyz;
        const float co01 = cxz * cyz - cxy * czz;
        const float co02 = cxy * cyz - cxz * cyy;
        const float det  = cxx * co00 + cxy * co01 + cxz * co02;
        const float id   = 1.0f / det;
        const float i00 = co00 * id, i01 = co01 * id, i02 = co02 * id;
        const float i11 = (cxx * czz - cxz * cxz) * id;
        const float i12 = (cxz * cxy - cxx * cyz) * id;
        const float i22 = (cxx * cyy - cxy * cxy) * id;
        const float cb0 = i00 * bt0 + i01 * bt1 + i02 * bt2;
        const float cb1 = i01 * bt0 + i11 * bt1 + i12 * bt2;
        const float cb2 = i02 * bt0 + i12 * bt1 + i22 * bt2;

        SA[w * 6 + 0][lane] = jn0; SA[w * 6 + 1][lane] = jn1; SA[w * 6 + 2][lane] = jn2;
        SA[w * 6 + 3][lane] = bt0; SA[w * 6 + 4][lane] = bt1; SA[w * 6 + 5][lane] = bt2;
        SB[w * 6 + 0][lane] = lj0; SB[w * 6 + 1][lane] = lj1; SB[w * 6 + 2][lane] = lj2;
        SB[w * 6 + 3][lane] = -cb0; SB[w * 6 + 4][lane] = -cb1; SB[w * 6 + 5][lane] = -cb2;
        __syncthreads();

#pragma unroll
        for (int k = 0; k < 24; k++) {
            const float4 a4 = *reinterpret_cast<const float4*>(&SA[k][d0]);
            const float4 b4 = *reinterpret_cast<const float4*>(&SB[k][eo0]);
            macc[0][0] += a4.x * b4.x; macc[0][1] += a4.x * b4.y; macc[0][2] += a4.x * b4.z; macc[0][3] += a4.x * b4.w;
            macc[1][0] += a4.y * b4.x; macc[1][1] += a4.y * b4.y; macc[1][2] += a4.y * b4.z; macc[1][3] += a4.y * b4.w;
            macc[2][0] += a4.z * b4.x; macc[2][1] += a4.z * b4.y; macc[2][2] += a4.z * b4.z; macc[2][3] += a4.z * b4.w;
            macc[3][0] += a4.w * b4.x; macc[3][1] += a4.w * b4.y; macc[3][2] += a4.w * b4.z; macc[3][3] += a4.w * b4.w;
        }
        __syncthreads();
    }

    float* Mb = M + b * 4096;
#pragma unroll
    for (int i = 0; i < 4; i++)
#pragma unroll
        for (int j = 0; j < 4; j++)
            atomicAdd(&Mb[(d0 + i) * 64 + (eo0 + j)], macc[i][j]);
}

// ---------------------------------------------------------------------------
// trace(sqrtm(M + delta*I)) via coupled Newton-Schulz, bf16-split MFMA matmuls.
// One block (4 waves) per batch matrix. All iterates are symmetric (polynomials
// in M), so MFMA B-operand fragments read row-major — no transposes.
// Update: Y' = Y*W, Z' = W*Z with W = 1.5I - 0.5*Z*Y  (W carries the 1/2).
// ---------------------------------------------------------------------------
__global__ __launch_bounds__(256) void ns_sqrt_kernel(const float* __restrict__ M,
                                                      float* __restrict__ out)
{
    const int b    = blockIdx.x;
    const int tid  = threadIdx.x;
    const int w    = tid >> 6;
    const int lane = tid & 63;
    const int quad = lane >> 4;
    const int mrow = lane & 15;
    const int r0   = w * 16;             // this wave's output row strip

    __shared__ __align__(16) unsigned short Yh[64 * PP], Yl[64 * PP];
    __shared__ __align__(16) unsigned short Zh[64 * PP], Zl[64 * PP];
    __shared__ __align__(16) unsigned short Wh[64 * PP], Wl[64 * PP];
    __shared__ float tr_s;

    const float* Mb = M + b * 4096;

    // trace of M (one wave)
    if (tid < 64) {
        float d = Mb[tid * 64 + tid];
#pragma unroll
        for (int off = 32; off; off >>= 1) d += __shfl_down(d, off, 64);
        if (tid == 0) tr_s = d;
    }
    __syncthreads();
    const float tr    = tr_s;
    const float delta = 3e-5f * tr;
    const float cnorm = tr + 64.f * delta;   // >= lambda_max of shifted matrix
    const float inv_c = 1.f / cnorm;

    // Y0 = (M + delta I)/c  (bf16 hi/lo split), Z0 = I
    for (int i = tid; i < 4096; i += 256) {
        const int r = i >> 6, col = i & 63;
        float v = Mb[i] * inv_c;
        if (r == col) v += delta * inv_c;
        const unsigned short h = f2bf(v);
        Yh[r * PP + col] = h;
        Yl[r * PP + col] = f2bf(v - bf2f(h));
        Zh[r * PP + col] = (r == col) ? (unsigned short)0x3f80 : (unsigned short)0;
        Zl[r * PP + col] = 0;
    }
    __syncthreads();

    const floatx4 zero4 = {0.f, 0.f, 0.f, 0.f};

    for (int it = 0; it < NS_ITERS; ++it) {
        // ---- phase 1: W = 1.5 I - 0.5 * (Z*Y) ----
        floatx4 accT[4];
#pragma unroll
        for (int c = 0; c < 4; c++) accT[c] = zero4;
#pragma unroll
        for (int ks = 0; ks < 2; ks++) {
            const int ko = ks * 32 + quad * 8;
            const short8 zah = *(const short8*)&Zh[(r0 + mrow) * PP + ko];
            const short8 zal = *(const short8*)&Zl[(r0 + mrow) * PP + ko];
#pragma unroll
            for (int c = 0; c < 4; c++) {
                const short8 ybh = *(const short8*)&Yh[(c * 16 + mrow) * PP + ko];
                const short8 ybl = *(const short8*)&Yl[(c * 16 + mrow) * PP + ko];
                accT[c] = __builtin_amdgcn_mfma_f32_16x16x32_bf16(zah, ybh, accT[c], 0, 0, 0);
                accT[c] = __builtin_amdgcn_mfma_f32_16x16x32_bf16(zah, ybl, accT[c], 0, 0, 0);
                accT[c] = __builtin_amdgcn_mfma_f32_16x16x32_bf16(zal, ybh, accT[c], 0, 0, 0);
            }
        }
        __syncthreads();   // T complete in regs; Wh/Wl free to overwrite
#pragma unroll
        for (int c = 0; c < 4; c++) {
#pragma unroll
            for (int r = 0; r < 4; r++) {
                const int row = r0 + quad * 4 + r;       // C/D layout: row=quad*4+reg
                const int col = c * 16 + mrow;           //             col=lane&15
                float v = -0.5f * accT[c][r];
                if (row == col) v += 1.5f;
                const unsigned short h = f2bf(v);
                Wh[row * PP + col] = h;
                Wl[row * PP + col] = f2bf(v - bf2f(h));
            }
        }
        __syncthreads();

        // ---- phase 2: Ynew = Y*W, Znew = W*Z (W carries the 1/2 factor) ----
        floatx4 accY[4], accZ[4];
#pragma unroll
        for (int c = 0; c < 4; c++) { accY[c] = zero4; accZ[c] = zero4; }
#pragma unroll
        for (int ks = 0; ks < 2; ks++) {
            const int ko = ks * 32 + quad * 8;
            const short8 yah = *(const short8*)&Yh[(r0 + mrow) * PP + ko];
            const short8 yal = *(const short8*)&Yl[(r0 + mrow) * PP + ko];
            const short8 wah = *(const short8*)&Wh[(r0 + mrow) * PP + ko];
            const short8 wal = *(const short8*)&Wl[(r0 + mrow) * PP + ko];
#pragma unroll
            for (int c = 0; c < 4; c++) {
                const short8 wbh = *(const short8*)&Wh[(c * 16 + mrow) * PP + ko];
                const short8 wbl = *(const short8*)&Wl[(c * 16 + mrow) * PP + ko];
                accY[c] = __builtin_amdgcn_mfma_f32_16x16x32_bf16(yah, wbh, accY[c], 0, 0, 0);
                accY[c] = __builtin_amdgcn_mfma_f32_16x16x32_bf16(yah, wbl, accY[c], 0, 0, 0);
                accY[c] = __builtin_amdgcn_mfma_f32_16x16x32_bf16(yal, wbh, accY[c], 0, 0, 0);
                const short8 zbh = *(const short8*)&Zh[(c * 16 + mrow) * PP + ko];
                const short8 zbl = *(const short8*)&Zl[(c * 16 + mrow) * PP + ko];
                accZ[c] = __builtin_amdgcn_mfma_f32_16x16x32_bf16(wah, zbh, accZ[c], 0, 0, 0);
                accZ[c] = __builtin_amdgcn_mfma_f32_16x16x32_bf16(wah, zbl, accZ[c], 0, 0, 0);
                accZ[c] = __builtin_amdgcn_mfma_f32_16x16x32_bf16(wal, zbh, accZ[c], 0, 0, 0);
            }
        }
        __syncthreads();   // all reads of Y,Z done; safe to overwrite in place
#pragma unroll
        for (int c = 0; c < 4; c++) {
#pragma unroll
            for (int r = 0; r < 4; r++) {
                const int row = r0 + quad * 4 + r;
                const int col = c * 16 + mrow;
                const float vy = accY[c][r];   // no extra 0.5 — W carries it
                const float vz = accZ[c][r];
                unsigned short h = f2bf(vy);
                Yh[row * PP + col] = h;
                Yl[row * PP + col] = f2bf(vy - bf2f(h));
                h = f2bf(vz);
                Zh[row * PP + col] = h;
                Zl[row * PP + col] = f2bf(vz - bf2f(h));
            }
        }
        __syncthreads();
    }

    // trace(Y) * sqrt(c): hi+lo recovers ~16-bit mantissa per diag element
    if (tid < 64) {
        float d = bf2f(Yh[tid * PP + tid]) + bf2f(Yl[tid * PP + tid]);
#pragma unroll
        for (int off = 32; off; off >>= 1) d += __shfl_down(d, off, 64);
        if (tid == 0) atomicAdd(out, d * sqrtf(cnorm) * (1.0f / BN));
    }
}

extern "C" void kernel_launch(void* const* d_in, const int* in_sizes, int n_in,
                              void* d_out, int out_size, void* d_ws, size_t ws_size,
                              hipStream_t stream) {
    const float* x  = (const float*)d_in[0];
    const float* J  = (const float*)d_in[1];
    const int*   e0 = (const int*)d_in[2];
    const int*   e1 = (const int*)d_in[3];
    const int E = in_sizes[2];

    int*   row_ptr = (int*)d_ws;
    float* M       = (float*)((char*)d_ws + 128 * 1024);

    hipMemsetAsync(M, 0, BN * 64 * 64 * sizeof(float), stream);
    hipMemsetAsync(d_out, 0, sizeof(float), stream);

    rowptr_kernel<<<(NV + 1 + 255) / 256, 256, 0, stream>>>(e0, E, row_ptr);
    node_kernel<<<dim3(256, BN), 256, 0, stream>>>(x, J, e1, row_ptr, M);
    ns_sqrt_kernel<<<BN, 256, 0, stream>>>(M, (float*)d_out);
}

// Round 5
// 247.993 us; speedup vs baseline: 4.6213x; 1.3779x over previous
//
#include <hip/hip_runtime.h>

constexpr int BN = 4;       // batches
constexpr int NV = 25600;   // vertices (160*160)
constexpr int DD = 64;      // D
constexpr int PP = 72;      // ns: bf16 LDS row pitch (16B-aligned rows)
constexpr int KP = 34;      // node: halfword pitch -> dword stride 17 (odd = conflict-free)
constexpr int NS_ITERS = 15;

typedef __attribute__((ext_vector_type(8))) short short8;
typedef __attribute__((ext_vector_type(4))) float floatx4;

__device__ __forceinline__ unsigned short f2bf(float x) {
    unsigned u = __float_as_uint(x);
    u += 0x7fffu + ((u >> 16) & 1u);        // round-to-nearest-even
    return (unsigned short)(u >> 16);
}
__device__ __forceinline__ float bf2f(unsigned short h) {
    return __uint_as_float(((unsigned)h) << 16);
}

__global__ void rowptr_kernel(const int* __restrict__ e0, int E, int* __restrict__ row_ptr) {
    int i = blockIdx.x * blockDim.x + threadIdx.x;
    if (i > NV) return;
    int lo = 0, hi = E;
    while (lo < hi) {
        int mid = (lo + hi) >> 1;
        if (e0[mid] < i) lo = mid + 1; else hi = mid;
    }
    row_ptr[i] = lo;
}

// load an MFMA A/B fragment (8 consecutive halfwords) from a [64][KP] panel
__device__ __forceinline__ short8 ldfrag(const unsigned short* a, int row, int quad) {
    const unsigned* p = (const unsigned*)(a + row * KP + quad * 8);  // even offset -> uint-aligned
    union { unsigned u[4]; short8 s; } t;
    t.u[0] = p[0]; t.u[1] = p[1]; t.u[2] = p[2]; t.u[3] = p[3];
    return t.s;
}

// One wave per node (lane = d column). 4 nodes per block per chunk.
// Phase 2 is an MFMA rank-32 (24 used + 8 zero-pad) update with bf16 hi/lo
// split (3 MFMAs: hh, hl, lh), fp32 accumulation in VGPRs across chunks.
__global__ __launch_bounds__(256, 4) void node_kernel(
    const float* __restrict__ x, const float* __restrict__ J,
    const int* __restrict__ e1, const int* __restrict__ row_ptr,
    float* __restrict__ M)
{
    const int b    = blockIdx.y;
    const int w    = __builtin_amdgcn_readfirstlane(threadIdx.x >> 6);  // uniform wave id
    const int lane = threadIdx.x & 63;   // d index in phase 1
    const int quad = lane >> 4;
    const int mrow = lane & 15;
    const int r0   = w * 16;             // this wave's output row strip

    // A^T, B^T panels: [d/e][k], k=0..23 written each chunk, 24..31 stay zero
    __shared__ unsigned short ATh[64 * KP], ATl[64 * KP];
    __shared__ unsigned short BTh[64 * KP], BTl[64 * KP];

    for (int i = threadIdx.x; i < 64 * KP; i += 256) {
        ATh[i] = 0; ATl[i] = 0; BTh[i] = 0; BTl[i] = 0;
    }
    __syncthreads();

    const floatx4 zero4 = {0.f, 0.f, 0.f, 0.f};
    floatx4 accM[4];
#pragma unroll
    for (int c = 0; c < 4; c++) accM[c] = zero4;

    const float* xb = x + (size_t)b * NV * 3;
    const float* Jb = J + (size_t)b * 3 * NV * DD;

    for (int chunk = blockIdx.x; chunk < NV / 4; chunk += gridDim.x) {
        const int n   = chunk * 4 + w;
        const int beg = row_ptr[n];
        const int deg = row_ptr[n + 1] - beg;

        // neighbor indices (scalar loads; padded with self -> zero contribution)
        int mm[6];
#pragma unroll
        for (int k = 0; k < 6; k++) {
            const int idx = beg + ((k < deg) ? k : 0);
            const int mv  = e1[idx];
            mm[k] = (k < deg) ? mv : n;
        }

        // issue ALL global loads up front (one latency window)
        const float* Jn = Jb + n * 3 * DD + lane;
        const float jn0 = Jn[0], jn1 = Jn[DD], jn2 = Jn[2 * DD];
        float jm0[6], jm1[6], jm2[6];
#pragma unroll
        for (int k = 0; k < 6; k++) {
            const float* Jm = Jb + mm[k] * 3 * DD + lane;
            jm0[k] = Jm[0]; jm1[k] = Jm[DD]; jm2[k] = Jm[2 * DD];
        }
        const float xn0 = xb[n * 3 + 0], xn1 = xb[n * 3 + 1], xn2 = xb[n * 3 + 2];
        float va0[6], va1[6], va2[6];
#pragma unroll
        for (int k = 0; k < 6; k++) {
            va0[k] = xn0 - xb[mm[k] * 3 + 0];
            va1[k] = xn1 - xb[mm[k] * 3 + 1];
            va2[k] = xn2 - xb[mm[k] * 3 + 2];
        }

        float lj0 = 0, lj1 = 0, lj2 = 0, bt0 = 0, bt1 = 0, bt2 = 0;
        float cxx = 0, cxy = 0, cxz = 0, cyy = 0, cyz = 0, czz = 0;
#pragma unroll
        for (int k = 0; k < 6; k++) {
            const float v0 = va0[k], v1 = va1[k], v2 = va2[k];
            const float t0 = jm0[k] - jn0, t1 = jm1[k] - jn1, t2 = jm2[k] - jn2;
            lj0 -= t0; lj1 -= t1; lj2 -= t2;
            bt0 += v1 * t2 - v2 * t1;
            bt1 += v2 * t0 - v0 * t2;
            bt2 += v0 * t1 - v1 * t0;
            const float s2 = v0 * v0 + v1 * v1 + v2 * v2;
            cxx += s2 - v0 * v0; cyy += s2 - v1 * v1; czz += s2 - v2 * v2;
            cxy -= v0 * v1; cxz -= v0 * v2; cyz -= v1 * v2;
        }
        // safety tail (never taken on this mesh: max degree 6)
        for (int e = beg + 6; e < beg + deg; e++) {
            const int m = e1[e];
            const float v0 = xn0 - xb[m * 3 + 0];
            const float v1 = xn1 - xb[m * 3 + 1];
            const float v2 = xn2 - xb[m * 3 + 2];
            const float* Jm = Jb + m * 3 * DD + lane;
            const float t0 = Jm[0] - jn0, t1 = Jm[DD] - jn1, t2 = Jm[2 * DD] - jn2;
            lj0 -= t0; lj1 -= t1; lj2 -= t2;
            bt0 += v1 * t2 - v2 * t1;
            bt1 += v2 * t0 - v0 * t2;
            bt2 += v0 * t1 - v1 * t0;
            const float s2 = v0 * v0 + v1 * v1 + v2 * v2;
            cxx += s2 - v0 * v0; cyy += s2 - v1 * v1; czz += s2 - v2 * v2;
            cxy -= v0 * v1; cxz -= v0 * v2; cyz -= v1 * v2;
        }

        lj0 *= 2.f; lj1 *= 2.f; lj2 *= 2.f;
        const float co00 = cyy * czz - cyz * cyz;
        const float co01 = cxz * cyz - cxy * czz;
        const float co02 = cxy * cyz - cxz * cyy;
        const float det  = cxx * co00 + cxy * co01 + cxz * co02;
        const float id   = 1.0f / det;
        const float i00 = co00 * id, i01 = co01 * id, i02 = co02 * id;
        const float i11 = (cxx * czz - cxz * cxz) * id;
        const float i12 = (cxz * cxy - cxx * cyz) * id;
        const float i22 = (cxx * cyy - cxy * cxy) * id;
        const float cb0 = i00 * bt0 + i01 * bt1 + i02 * bt2;
        const float cb1 = i01 * bt0 + i11 * bt1 + i12 * bt2;
        const float cb2 = i02 * bt0 + i12 * bt1 + i22 * bt2;

        // transposed bf16 hi/lo writeback: row d=lane, k = w*6 + i
        {
            const int kA = w * 6;
            float av[6] = {jn0, jn1, jn2, bt0, bt1, bt2};
            float bv[6] = {lj0, lj1, lj2, -cb0, -cb1, -cb2};
#pragma unroll
            for (int i = 0; i < 6; i++) {
                unsigned short h = f2bf(av[i]);
                ATh[lane * KP + kA + i] = h;
                ATl[lane * KP + kA + i] = f2bf(av[i] - bf2f(h));
                h = f2bf(bv[i]);
                BTh[lane * KP + kA + i] = h;
                BTl[lane * KP + kA + i] = f2bf(bv[i] - bf2f(h));
            }
        }
        __syncthreads();

        // phase 2: 16x16x32 MFMA over K=32 (24 used), 4 col-tiles per wave
        const short8 ah = ldfrag(ATh, r0 + mrow, quad);
        const short8 al = ldfrag(ATl, r0 + mrow, quad);
#pragma unroll
        for (int c = 0; c < 4; c++) {
            const short8 bh = ldfrag(BTh, c * 16 + mrow, quad);
            const short8 bl = ldfrag(BTl, c * 16 + mrow, quad);
            accM[c] = __builtin_amdgcn_mfma_f32_16x16x32_bf16(ah, bh, accM[c], 0, 0, 0);
            accM[c] = __builtin_amdgcn_mfma_f32_16x16x32_bf16(ah, bl, accM[c], 0, 0, 0);
            accM[c] = __builtin_amdgcn_mfma_f32_16x16x32_bf16(al, bh, accM[c], 0, 0, 0);
        }
        __syncthreads();
    }

    float* Mb = M + b * 4096;
#pragma unroll
    for (int c = 0; c < 4; c++)
#pragma unroll
        for (int r = 0; r < 4; r++)
            atomicAdd(&Mb[(r0 + quad * 4 + r) * 64 + (c * 16 + mrow)], accM[c][r]);
}

// ---------------------------------------------------------------------------
// trace(sqrtm(M + delta*I)) via coupled Newton-Schulz, bf16-split MFMA matmuls.
// 1024 threads = 16 waves in a 4x4 tile grid (each wave owns a 16x16 output
// tile) -> 4 waves/SIMD of TLP on the single resident CU.
// ---------------------------------------------------------------------------
__global__ __launch_bounds__(1024) void ns_sqrt_kernel(const float* __restrict__ M,
                                                       float* __restrict__ out)
{
    const int b    = blockIdx.x;
    const int tid  = threadIdx.x;
    const int w    = tid >> 6;
    const int lane = tid & 63;
    const int quad = lane >> 4;
    const int mrow = lane & 15;
    const int r0   = (w & 3) * 16;       // output tile row strip
    const int c0   = (w >> 2) * 16;      // output tile col strip

    __shared__ __align__(16) unsigned short Yh[64 * PP], Yl[64 * PP];
    __shared__ __align__(16) unsigned short Zh[64 * PP], Zl[64 * PP];
    __shared__ __align__(16) unsigned short Wh[64 * PP], Wl[64 * PP];
    __shared__ float tr_s;

    const float* Mb = M + b * 4096;

    // trace of M (one wave)
    if (tid < 64) {
        float d = Mb[tid * 64 + tid];
#pragma unroll
        for (int off = 32; off; off >>= 1) d += __shfl_down(d, off, 64);
        if (tid == 0) tr_s = d;
    }
    __syncthreads();
    const float tr    = tr_s;
    const float delta = 3e-5f * tr;
    const float cnorm = tr + 64.f * delta;   // >= lambda_max of shifted matrix
    const float inv_c = 1.f / cnorm;

    // Y0 = (M + delta I)/c  (bf16 hi/lo split), Z0 = I
    for (int i = tid; i < 4096; i += 1024) {
        const int r = i >> 6, col = i & 63;
        float v = Mb[i] * inv_c;
        if (r == col) v += delta * inv_c;
        const unsigned short h = f2bf(v);
        Yh[r * PP + col] = h;
        Yl[r * PP + col] = f2bf(v - bf2f(h));
        Zh[r * PP + col] = (r == col) ? (unsigned short)0x3f80 : (unsigned short)0;
        Zl[r * PP + col] = 0;
    }
    __syncthreads();

    const floatx4 zero4 = {0.f, 0.f, 0.f, 0.f};

    for (int it = 0; it < NS_ITERS; ++it) {
        // ---- phase 1: W = 1.5 I - 0.5 * (Z*Y) ----
        floatx4 accT = zero4;
#pragma unroll
        for (int ks = 0; ks < 2; ks++) {
            const int ko = ks * 32 + quad * 8;
            const short8 zah = *(const short8*)&Zh[(r0 + mrow) * PP + ko];
            const short8 zal = *(const short8*)&Zl[(r0 + mrow) * PP + ko];
            const short8 ybh = *(const short8*)&Yh[(c0 + mrow) * PP + ko];
            const short8 ybl = *(const short8*)&Yl[(c0 + mrow) * PP + ko];
            accT = __builtin_amdgcn_mfma_f32_16x16x32_bf16(zah, ybh, accT, 0, 0, 0);
            accT = __builtin_amdgcn_mfma_f32_16x16x32_bf16(zah, ybl, accT, 0, 0, 0);
            accT = __builtin_amdgcn_mfma_f32_16x16x32_bf16(zal, ybh, accT, 0, 0, 0);
        }
        __syncthreads();   // all waves done reading W(prev) via phase 2 & T in regs
#pragma unroll
        for (int r = 0; r < 4; r++) {
            const int row = r0 + quad * 4 + r;       // C/D layout: row=quad*4+reg
            const int col = c0 + mrow;               //             col=lane&15
            float v = -0.5f * accT[r];
            if (row == col) v += 1.5f;
            const unsigned short h = f2bf(v);
            Wh[row * PP + col] = h;
            Wl[row * PP + col] = f2bf(v - bf2f(h));
        }
        __syncthreads();

        // ---- phase 2: Ynew = Y*W, Znew = W*Z (W carries the 1/2 factor) ----
        floatx4 accY = zero4, accZ = zero4;
#pragma unroll
        for (int ks = 0; ks < 2; ks++) {
            const int ko = ks * 32 + quad * 8;
            const short8 yah = *(const short8*)&Yh[(r0 + mrow) * PP + ko];
            const short8 yal = *(const short8*)&Yl[(r0 + mrow) * PP + ko];
            const short8 wah = *(const short8*)&Wh[(r0 + mrow) * PP + ko];
            const short8 wal = *(const short8*)&Wl[(r0 + mrow) * PP + ko];
            const short8 wbh = *(const short8*)&Wh[(c0 + mrow) * PP + ko];
            const short8 wbl = *(const short8*)&Wl[(c0 + mrow) * PP + ko];
            const short8 zbh = *(const short8*)&Zh[(c0 + mrow) * PP + ko];
            const short8 zbl = *(const short8*)&Zl[(c0 + mrow) * PP + ko];
            accY = __builtin_amdgcn_mfma_f32_16x16x32_bf16(yah, wbh, accY, 0, 0, 0);
            accY = __builtin_amdgcn_mfma_f32_16x16x32_bf16(yah, wbl, accY, 0, 0, 0);
            accY = __builtin_amdgcn_mfma_f32_16x16x32_bf16(yal, wbh, accY, 0, 0, 0);
            accZ = __builtin_amdgcn_mfma_f32_16x16x32_bf16(wah, zbh, accZ, 0, 0, 0);
            accZ = __builtin_amdgcn_mfma_f32_16x16x32_bf16(wah, zbl, accZ, 0, 0, 0);
            accZ = __builtin_amdgcn_mfma_f32_16x16x32_bf16(wal, zbh, accZ, 0, 0, 0);
        }
        __syncthreads();   // all reads of Y,Z done; safe to overwrite in place
#pragma unroll
        for (int r = 0; r < 4; r++) {
            const int row = r0 + quad * 4 + r;
            const int col = c0 + mrow;
            const float vy = accY[r];
            const float vz = accZ[r];
            unsigned short h = f2bf(vy);
            Yh[row * PP + col] = h;
            Yl[row * PP + col] = f2bf(vy - bf2f(h));
            h = f2bf(vz);
            Zh[row * PP + col] = h;
            Zl[row * PP + col] = f2bf(vz - bf2f(h));
        }
        __syncthreads();
    }

    // trace(Y) * sqrt(c): hi+lo recovers ~16-bit mantissa per diag element
    if (tid < 64) {
        float d = bf2f(Yh[tid * PP + tid]) + bf2f(Yl[tid * PP + tid]);
#pragma unroll
        for (int off = 32; off; off >>= 1) d += __shfl_down(d, off, 64);
        if (tid == 0) atomicAdd(out, d * sqrtf(cnorm) * (1.0f / BN));
    }
}

extern "C" void kernel_launch(void* const* d_in, const int* in_sizes, int n_in,
                              void* d_out, int out_size, void* d_ws, size_t ws_size,
                              hipStream_t stream) {
    const float* x  = (const float*)d_in[0];
    const float* J  = (const float*)d_in[1];
    const int*   e0 = (const int*)d_in[2];
    const int*   e1 = (const int*)d_in[3];
    const int E = in_sizes[2];

    int*   row_ptr = (int*)d_ws;
    float* M       = (float*)((char*)d_ws + 128 * 1024);

    hipMemsetAsync(M, 0, BN * 64 * 64 * sizeof(float), stream);
    hipMemsetAsync(d_out, 0, sizeof(float), stream);

    rowptr_kernel<<<(NV + 1 + 255) / 256, 256, 0, stream>>>(e0, E, row_ptr);
    node_kernel<<<dim3(256, BN), 256, 0, stream>>>(x, J, e1, row_ptr, M);
    ns_sqrt_kernel<<<BN, 1024, 0, stream>>>(M, (float*)d_out);
}